// Round 2
// baseline (465.437 us; speedup 1.0000x reference)
//
#include <hip/hip_runtime.h>
#include <hip/hip_bf16.h>
#include <stdint.h>

// Problem dims (fixed by the reference)
constexpr int Mdim = 256;    // batch
constexpr int Ndim = 4096;   // codes E
constexpr int Kdim = 16384;  // EMB

typedef __attribute__((ext_vector_type(8))) short short8;  // 8 x bf16 (4 VGPR)
typedef __attribute__((ext_vector_type(4))) float f32x4;

// ---------- fused-convert GEMM config (fast path) ----------
constexpr int KS   = 8;             // split-K
constexpr int KC   = Kdim / KS;     // 2048
constexpr int BK   = 64;            // K per LDS chunk (bf16 MFMA K-tile group)
constexpr int NIT  = KC / BK;       // 32 sub-iterations
constexpr int NMAC = NIT / 4;       // 8 macros (256 fp32 cols each)
constexpr int NKC  = Kdim / 64;     // 256 k-chunks per 128-row block
// swizzled tile: [oct 8][row 128][8 elems] bf16 = 16 KB, contiguous
constexpr int TILE_ELEMS = 8 * 128 * 8;  // 8192

// ws layout (bytes)
constexpr size_t X_SWZ_OFF = 0;
constexpr size_t X_SWZ_SZ  = (size_t)Mdim * Kdim * 2;           // 8 MiB
constexpr size_t PART_OFF  = X_SWZ_OFF + X_SWZ_SZ;
constexpr size_t PART_SZ   = (size_t)KS * Mdim * Ndim * 4;      // 32 MiB
constexpr size_t NEED_FAST = PART_OFF + PART_SZ;                // 40 MiB

// fallback fused gemm (atomic mode) config
constexpr int FMT = 128, FNT = 128, FBK = 32;
constexpr int KS_MID = 16;

// packed fp32x2 -> bf16x2 RNE (v_cvt_pk_bf16_f32 on gfx950)
__device__ __forceinline__ unsigned int cvt2(float lo, float hi) {
  union { __hip_bfloat162 h; unsigned int u; } v;
  v.h = __float22bfloat162_rn(make_float2(lo, hi));
  return v.u;
}

__device__ __forceinline__ void async16(const void* g, void* l) {
  __builtin_amdgcn_global_load_lds(
      (const __attribute__((address_space(1))) void*)g,
      (__attribute__((address_space(3))) void*)l, 16, 0, 0);
}

// ============================================================
// Pass 1: x only -> bf16 fragment-tile swizzle (8 MiB out).
// 128 blocks; same layout the GEMM's A-stager expects.
// ============================================================
__global__ __launch_bounds__(256) void k_prep(const float* __restrict__ x,
                                              unsigned short* __restrict__ x_swz) {
  __shared__ unsigned short sw[4][8][128][8];  // [kc_l][oct][row][8] = 64 KiB
  const int idx = blockIdx.x;     // 0..127
  const int nt = idx >> 6;        // 0..1 (two 128-row tiles of x)
  const int p  = idx & 63;        // 256-k panel
  const int t = threadIdx.x;
  const int r = t >> 1;           // row within 128-tile
  const int h = t & 1;            // half of the 256-k panel

  const float4* s4 = (const float4*)(x + (size_t)(nt * 128 + r) * Kdim + p * 256 + h * 128);
  float4 v[32];
#pragma unroll
  for (int g = 0; g < 32; ++g) v[g] = s4[g];   // 512 B sequential per thread

#pragma unroll
  for (int c = 0; c < 16; ++c) {  // 8-elem chunks: k_local = h*128 + c*8
    const int kc_l = h * 2 + (c >> 3);
    const int oct  = c & 7;
    float4 a = v[2 * c], d = v[2 * c + 1];
    union { short8 s; unsigned int u[4]; } pk;
    pk.u[0] = cvt2(a.x, a.y); pk.u[1] = cvt2(a.z, a.w);
    pk.u[2] = cvt2(d.x, d.y); pk.u[3] = cvt2(d.z, d.w);
    *(short8*)&sw[kc_l][oct][r][0] = pk.s;
  }
  __syncthreads();

  // sequential 64 KiB block store: cells (nt, p*4 .. p*4+3) are adjacent
  const size_t base = ((size_t)nt * NKC + (size_t)p * 4) * TILE_ELEMS;  // in shorts
  const float4* lsrc = (const float4*)&sw[0][0][0][0];
  float4* gdst = (float4*)(x_swz + base);
#pragma unroll
  for (int i = 0; i < 16; ++i) gdst[i * 256 + t] = lsrc[i * 256 + t];
}

// ============================================================
// Pass 2: fused-convert bf16 MFMA GEMM. BM=256 (all of M), BN=128.
// Grid (32 nb, 8 kz) = 256 blocks = 1 block/CU, 512 threads (8 waves).
//   A: x_swz (bf16, swizzled) via global_load_lds width=16, double-buffered.
//   B: e fp32 streamed ONCE from HBM in MACRO bursts of 256 cols:
//      4-thread row-groups read 1 KiB contiguous per row (DRAM page friendly),
//      early-convert to a 32-VGPR bf16 stash, dribble one 64-col chunk per
//      sub-iter into quad-buffered ldsB (slot = chunk). All slot writes are
//      barrier-separated from same-slot reads -> plain __syncthreads works.
// part[z][m][n] = esq_slice(z,n) - 2 * x.e |_kslice(z)
// ============================================================
__global__ __launch_bounds__(512, 2) void k_gemm_f(const unsigned short* __restrict__ x_swz,
                                                   const float* __restrict__ e,
                                                   float* __restrict__ part) {
  __shared__ unsigned short ldsA[2][2][8][128][8];  // [buf][nt][oct][row][8] = 64 KiB
  __shared__ unsigned short ldsB[4][8][128][8];     // [slot][oct][row][8]    = 64 KiB
  __shared__ float esq_sh[128];
  const int t = threadIdx.x;
  const int nb = blockIdx.x;   // 0..31
  const int kz = blockIdx.y;   // 0..7
  const int n0 = nb * 128;
  const int k0 = kz * KC;

  const int wave = t >> 6, lane = t & 63;
  const int wm = (wave & 3) * 64;   // 4-way M split over 256 rows
  const int wn = (wave >> 2) * 64;  // 2-way N split over 128 cols
  const int lcol = lane & 15, quad = lane >> 4;

  // A staging: two x_swz row-tiles (nt=0,1), k-chunks kz*NIT + it
  const unsigned short* A0 = x_swz + ((size_t)(0 * NKC) + kz * NIT) * TILE_ELEMS;
  const unsigned short* A1 = x_swz + ((size_t)(1 * NKC) + kz * NIT) * TILE_ELEMS;

  // B per-thread: row br = t>>2 (0..127), chunk kq = t&3 (64 fp32 cols of macro)
  const int br = t >> 2, kq = t & 3;
  const float* ep = e + (size_t)(n0 + br) * Kdim + k0 + kq * 64;

  float4 v4[16];   // transient fp32 macro burst (64 floats)
  short8 st[8];    // bf16 stash: this thread's 64-col chunk of current macro
  float sq = 0.0f;

  auto issueMac = [&](int M) {
    const float4* p4 = (const float4*)(ep + (size_t)M * 256);
#pragma unroll
    for (int g = 0; g < 16; ++g) v4[g] = p4[g];  // 4-thread group: 1 KiB/row burst
  };
  auto cvtMac = [&]() {
#pragma unroll
    for (int o = 0; o < 8; ++o) {
      float4 a = v4[2 * o], b = v4[2 * o + 1];
      sq += a.x * a.x + a.y * a.y + a.z * a.z + a.w * a.w
          + b.x * b.x + b.y * b.y + b.z * b.z + b.w * b.w;
      union { short8 s; unsigned int u[4]; } pk;
      pk.u[0] = cvt2(a.x, a.y); pk.u[1] = cvt2(a.z, a.w);
      pk.u[2] = cvt2(b.x, b.y); pk.u[3] = cvt2(b.z, b.w);
      st[o] = pk.s;
    }
  };
  auto writeChunk = [&](int w) {   // threads owning chunk w write slot w
    if (kq == w) {
#pragma unroll
      for (int o = 0; o < 8; ++o) *(short8*)&ldsB[w][o][br][0] = st[o];
    }
  };
  auto stageA = [&](int buf, int it) {
    const unsigned short* a0 = A0 + (size_t)it * TILE_ELEMS;
    const unsigned short* a1 = A1 + (size_t)it * TILE_ELEMS;
    unsigned short* d0 = &ldsA[buf][0][0][0][0];
    unsigned short* d1 = &ldsA[buf][1][0][0][0];
#pragma unroll
    for (int j = 0; j < 2; ++j) {
      int cell = j * 512 + t;
      async16(a0 + (size_t)cell * 8, d0 + cell * 8);
      async16(a1 + (size_t)cell * 8, d1 + cell * 8);
    }
  };

  f32x4 acc[4][4] = {};

  // prologue: macro 0 -> stash -> slots 0..2 (chunk 3 written at it=0)
  issueMac(0);
  stageA(0, 0);
  cvtMac();
  writeChunk(0); writeChunk(1); writeChunk(2);
  __syncthreads();

#pragma unroll 4
  for (int it = 0; it < NIT; ++it) {
    const int m = it >> 2, c = it & 3, cur = it & 1;
    if (c == 0 && m + 1 < NMAC) issueMac(m + 1);   // 1 KiB/row macro burst
    if (it + 1 < NIT) stageA(cur ^ 1, it + 1);     // async A into other buffer

    // frags + MFMA (read ldsA[cur], ldsB[slot c])
#pragma unroll
    for (int s = 0; s < 2; ++s) {
      const int oct = s * 4 + quad;
      short8 af[4], bfv[4];
#pragma unroll
      for (int mi = 0; mi < 4; ++mi) {
        const int mr = wm + mi * 16 + lcol;
        af[mi] = *(const short8*)&ldsA[cur][mr >> 7][oct][mr & 127][0];
      }
#pragma unroll
      for (int ni = 0; ni < 4; ++ni)
        bfv[ni] = *(const short8*)&ldsB[c][oct][wn + ni * 16 + lcol][0];
#pragma unroll
      for (int mi = 0; mi < 4; ++mi)
#pragma unroll
        for (int ni = 0; ni < 4; ++ni)
          acc[mi][ni] = __builtin_amdgcn_mfma_f32_16x16x32_bf16(af[mi], bfv[ni], acc[mi][ni], 0, 0, 0);
    }

    if (c == 0) {
      writeChunk(3);                    // macro m chunk 3 (from old stash)
      if (m + 1 < NMAC) cvtMac();       // then overwrite stash with macro m+1
    } else if (m + 1 < NMAC) {
      writeChunk(c - 1);                // macro m+1 chunk c-1
    }
    __syncthreads();  // drains A asyncs + B burst loads + fences ds writes
  }

  // ||e||^2 slice partial: 4 threads per row -> shfl reduce
  sq += __shfl_xor(sq, 1, 64);
  sq += __shfl_xor(sq, 2, 64);
  if (kq == 0) esq_sh[br] = sq;
  __syncthreads();

  // epilogue: C/D layout col=lane&15, row=quad*4+reg
  float* base = part + (size_t)kz * Mdim * Ndim;
#pragma unroll
  for (int ni = 0; ni < 4; ++ni) {
    const int cl = wn + ni * 16 + lcol;
    const float ev = esq_sh[cl];
#pragma unroll
    for (int mi = 0; mi < 4; ++mi)
#pragma unroll
      for (int reg = 0; reg < 4; ++reg) {
        const int row = wm + mi * 16 + quad * 4 + reg;
        base[(size_t)row * Ndim + n0 + cl] = ev - 2.0f * acc[mi][ni][reg];
      }
  }
}

// ============================================================
// Fused select: split-K reduce (compile-time NZ, unrolled) + top-2
// + exact fp32 refine + one-hot write
// ============================================================
template <int NZ>
__global__ __launch_bounds__(256) void k_select_t(const float* __restrict__ part,
                                                  const float* __restrict__ x,
                                                  const float* __restrict__ e,
                                                  float* __restrict__ out) {
  __shared__ float sv1[256], sv2[256];
  __shared__ int   si1[256], si2[256];
  __shared__ float s1[256], s2[256];
  __shared__ int win_sh;
  const int b = blockIdx.x, t = threadIdx.x;

  float v1 = 3.4e38f, v2 = 3.4e38f; int i1 = 0, i2 = 1;
  auto upd = [&](float v, int idx) {
    if (v < v1)      { v2 = v1; i2 = i1; v1 = v; i1 = idx; }
    else if (v < v2) { v2 = v;  i2 = idx; }
  };
#pragma unroll
  for (int i = 0; i < Ndim / 4 / 256; ++i) {
    int q = t + i * 256;  // float4 index over n
    float sx = 0.f, sy = 0.f, sz = 0.f, sw = 0.f;
#pragma unroll
    for (int z = 0; z < NZ; ++z) {
      float4 v = ((const float4*)part)[((size_t)z * Mdim + b) * (Ndim / 4) + q];
      sx += v.x; sy += v.y; sz += v.z; sw += v.w;
    }
    upd(sx, 4 * q + 0); upd(sy, 4 * q + 1); upd(sz, 4 * q + 2); upd(sw, 4 * q + 3);
  }
  sv1[t] = v1; si1[t] = i1; sv2[t] = v2; si2[t] = i2;
  __syncthreads();
  for (int sOff = 128; sOff > 0; sOff >>= 1) {
    if (t < sOff) {
      float bv1 = sv1[t + sOff], bv2 = sv2[t + sOff];
      int   bi1 = si1[t + sOff], bi2 = si2[t + sOff];
      float av1 = sv1[t],        av2 = sv2[t];
      int   ai1 = si1[t],        ai2 = si2[t];
      if (bv1 < av1)      { av2 = av1; ai2 = ai1; av1 = bv1; ai1 = bi1; }
      else if (bv1 < av2) { av2 = bv1; ai2 = bi1; }
      if (bv2 < av2)      { av2 = bv2; ai2 = bi2; }
      sv1[t] = av1; si1[t] = ai1; sv2[t] = av2; si2[t] = ai2;
    }
    __syncthreads();
  }
  const int c1 = si1[0], c2 = si2[0];

  // exact fp32 distances for the two candidates
  const float4* xb = (const float4*)(x + (size_t)b  * Kdim);
  const float4* e1 = (const float4*)(e + (size_t)c1 * Kdim);
  const float4* e2 = (const float4*)(e + (size_t)c2 * Kdim);
  float a1 = 0.f, a2 = 0.f;
#pragma unroll 4
  for (int i = 0; i < Kdim / 4 / 256; ++i) {
    int q = t + i * 256;
    float4 xv  = xb[q];
    float4 ev1 = e1[q];
    float4 ev2 = e2[q];
    a1 += ev1.x * (ev1.x - 2.f * xv.x) + ev1.y * (ev1.y - 2.f * xv.y)
        + ev1.z * (ev1.z - 2.f * xv.z) + ev1.w * (ev1.w - 2.f * xv.w);
    a2 += ev2.x * (ev2.x - 2.f * xv.x) + ev2.y * (ev2.y - 2.f * xv.y)
        + ev2.z * (ev2.z - 2.f * xv.z) + ev2.w * (ev2.w - 2.f * xv.w);
  }
  s1[t] = a1; s2[t] = a2;
  __syncthreads();
  for (int sOff = 128; sOff > 0; sOff >>= 1) {
    if (t < sOff) { s1[t] += s1[t + sOff]; s2[t] += s2[t + sOff]; }
    __syncthreads();
  }
  if (t == 0) {
    float d1 = s1[0], d2 = s2[0];
    win_sh = (d2 < d1 || (d2 == d1 && c2 < c1)) ? c2 : c1;  // np.argmin tie: smaller idx
  }
  __syncthreads();

  const int win = win_sh;
  float* outb = out + (size_t)b * Ndim;
#pragma unroll
  for (int g = 0; g < 4; ++g) {
    int q = g * 256 + t;
    float4 v;
    v.x = (win == 4 * q + 0) ? 1.f : 0.f;
    v.y = (win == 4 * q + 1) ? 1.f : 0.f;
    v.z = (win == 4 * q + 2) ? 1.f : 0.f;
    v.w = (win == 4 * q + 3) ? 1.f : 0.f;
    ((float4*)outb)[q] = v;
  }
}

// ============================================================
// Fallback tier (tiny/no workspace): fused gemm with atomics into out.
// ============================================================
__global__ __launch_bounds__(256) void k_gemm_fused(const float* __restrict__ x,
                                                    const float* __restrict__ e,
                                                    float* __restrict__ dst,
                                                    int ws_mode) {
  __shared__ short lds[2][2][4][128][8];
  __shared__ float esq_part[256];
  __shared__ float esq_sh[128];
  const int t  = threadIdx.x;
  const int n0 = blockIdx.x * FNT;
  const int m0 = blockIdx.y * FMT;
  const int kz = blockIdx.z;
  const int KCF = Kdim / KS_MID;
  const int NITF = KCF / FBK;
  const int k0 = kz * KCF;
  const int r  = t >> 1;
  const int kq = (t & 1) * 16;
  const int g0 = (t & 1) * 2;
  const float* xp = x + (size_t)(m0 + r) * Kdim + k0 + kq;
  const float* ep = e + (size_t)(n0 + r) * Kdim + k0 + kq;
  const int wave = t >> 6, lane = t & 63;
  const int wm = (wave & 1) * 64, wn = (wave >> 1) * 64;
  const int lcol = lane & 15, quad = lane >> 4;

  f32x4 acc[4][4] = {};
  float esq_acc = 0.0f;
  float4 bufA[4], bufB[4];
#pragma unroll
  for (int g = 0; g < 4; ++g) {
    bufA[g] = ((const float4*)xp)[g];
    bufB[g] = ((const float4*)ep)[g];
  }
  auto stagef = [&](int buf) {
    union { short8 s; unsigned int u[4]; } pa0, pa1, pb0, pb1;
    pa0.u[0] = cvt2(bufA[0].x, bufA[0].y); pa0.u[1] = cvt2(bufA[0].z, bufA[0].w);
    pa0.u[2] = cvt2(bufA[1].x, bufA[1].y); pa0.u[3] = cvt2(bufA[1].z, bufA[1].w);
    pa1.u[0] = cvt2(bufA[2].x, bufA[2].y); pa1.u[1] = cvt2(bufA[2].z, bufA[2].w);
    pa1.u[2] = cvt2(bufA[3].x, bufA[3].y); pa1.u[3] = cvt2(bufA[3].z, bufA[3].w);
    pb0.u[0] = cvt2(bufB[0].x, bufB[0].y); pb0.u[1] = cvt2(bufB[0].z, bufB[0].w);
    pb0.u[2] = cvt2(bufB[1].x, bufB[1].y); pb0.u[3] = cvt2(bufB[1].z, bufB[1].w);
    pb1.u[0] = cvt2(bufB[2].x, bufB[2].y); pb1.u[1] = cvt2(bufB[2].z, bufB[2].w);
    pb1.u[2] = cvt2(bufB[3].x, bufB[3].y); pb1.u[3] = cvt2(bufB[3].z, bufB[3].w);
#pragma unroll
    for (int g = 0; g < 4; ++g)
      esq_acc += bufB[g].x * bufB[g].x + bufB[g].y * bufB[g].y
               + bufB[g].z * bufB[g].z + bufB[g].w * bufB[g].w;
    *(short8*)&lds[buf][0][g0    ][r][0] = pa0.s;
    *(short8*)&lds[buf][0][g0 + 1][r][0] = pa1.s;
    *(short8*)&lds[buf][1][g0    ][r][0] = pb0.s;
    *(short8*)&lds[buf][1][g0 + 1][r][0] = pb1.s;
  };
  stagef(0);
  __syncthreads();
  for (int it = 0; it < NITF; ++it) {
    const int cur = it & 1;
    if (it + 1 < NITF) {
      const float* xn = xp + (size_t)(it + 1) * FBK;
      const float* en = ep + (size_t)(it + 1) * FBK;
#pragma unroll
      for (int g = 0; g < 4; ++g) {
        bufA[g] = ((const float4*)xn)[g];
        bufB[g] = ((const float4*)en)[g];
      }
    }
    short8 af[4], bfr[4];
#pragma unroll
    for (int mi = 0; mi < 4; ++mi)
      af[mi] = *(const short8*)&lds[cur][0][quad][wm + mi * 16 + lcol][0];
#pragma unroll
    for (int ni = 0; ni < 4; ++ni)
      bfr[ni] = *(const short8*)&lds[cur][1][quad][wn + ni * 16 + lcol][0];
#pragma unroll
    for (int mi = 0; mi < 4; ++mi)
#pragma unroll
      for (int ni = 0; ni < 4; ++ni)
        acc[mi][ni] = __builtin_amdgcn_mfma_f32_16x16x32_bf16(af[mi], bfr[ni], acc[mi][ni], 0, 0, 0);
    if (it + 1 < NITF) {
      stagef(cur ^ 1);
      __syncthreads();
    }
  }
  esq_part[t] = esq_acc;
  __syncthreads();
  if (t < 128) esq_sh[t] = esq_part[2 * t] + esq_part[2 * t + 1];
  __syncthreads();
  if (ws_mode) {
    float* base = dst + (size_t)kz * Mdim * Ndim;
#pragma unroll
    for (int mi = 0; mi < 4; ++mi)
#pragma unroll
      for (int ni = 0; ni < 4; ++ni)
#pragma unroll
        for (int reg = 0; reg < 4; ++reg) {
          int row = m0 + wm + mi * 16 + quad * 4 + reg;
          int cl  = wn + ni * 16 + lcol;
          base[(size_t)row * Ndim + n0 + cl] = esq_sh[cl] - 2.0f * acc[mi][ni][reg];
        }
  } else {
#pragma unroll
    for (int mi = 0; mi < 4; ++mi)
#pragma unroll
      for (int ni = 0; ni < 4; ++ni)
#pragma unroll
        for (int reg = 0; reg < 4; ++reg) {
          int row = m0 + wm + mi * 16 + quad * 4 + reg;
          int cl  = wn + ni * 16 + lcol;
          atomicAdd(&dst[(size_t)row * Ndim + n0 + cl], esq_sh[cl] - 2.0f * acc[mi][ni][reg]);
        }
  }
}

extern "C" void kernel_launch(void* const* d_in, const int* in_sizes, int n_in,
                              void* d_out, int out_size, void* d_ws, size_t ws_size,
                              hipStream_t stream) {
  (void)in_sizes; (void)n_in; (void)out_size;
  const float* x = (const float*)d_in[0];  // [256, 16384] fp32
  const float* e = (const float*)d_in[1];  // [4096, 16384] fp32
  float* out = (float*)d_out;
  char* ws = (char*)d_ws;

  if (ws_size >= NEED_FAST) {
    unsigned short* x_swz = (unsigned short*)(ws + X_SWZ_OFF);
    float* part = (float*)(ws + PART_OFF);
    hipLaunchKernelGGL(k_prep, dim3(128), dim3(256), 0, stream, x, x_swz);
    hipLaunchKernelGGL(k_gemm_f, dim3(Ndim / 128, KS), dim3(512), 0, stream,
                       x_swz, e, part);
    hipLaunchKernelGGL(k_select_t<KS>, dim3(Mdim), dim3(256), 0, stream, part, x, e, out);
  } else if (ws_size >= (size_t)KS_MID * Mdim * Ndim * 4) {
    float* part = (float*)ws;
    hipLaunchKernelGGL(k_gemm_fused, dim3(Ndim / FNT, Mdim / FMT, KS_MID), dim3(256), 0, stream,
                       x, e, part, 1);
    hipLaunchKernelGGL(k_select_t<KS_MID>, dim3(Mdim), dim3(256), 0, stream, part, x, e, out);
  } else {
    hipMemsetAsync(d_out, 0, (size_t)Mdim * Ndim * sizeof(float), stream);
    hipLaunchKernelGGL(k_gemm_fused, dim3(Ndim / FNT, Mdim / FMT, KS_MID), dim3(256), 0, stream,
                       x, e, out, 0);
    hipLaunchKernelGGL(k_select_t<1>, dim3(Mdim), dim3(256), 0, stream, out, x, e, out);
  }
}

// Round 3
// 443.120 us; speedup vs baseline: 1.0504x; 1.0504x over previous
//
#include <hip/hip_runtime.h>
#include <hip/hip_bf16.h>
#include <stdint.h>

// Problem dims (fixed by the reference)
constexpr int Mdim = 256;    // batch
constexpr int Ndim = 4096;   // codes E
constexpr int Kdim = 16384;  // EMB

typedef __attribute__((ext_vector_type(8))) short short8;  // 8 x bf16 (4 VGPR)
typedef __attribute__((ext_vector_type(4))) float f32x4;

// ---------- fused-convert GEMM config (fast path) ----------
constexpr int KS   = 8;             // split-K
constexpr int KC   = Kdim / KS;     // 2048
constexpr int BK   = 64;            // K per LDS chunk (bf16 MFMA K-tile group)
constexpr int NIT  = KC / BK;       // 32 sub-iterations
constexpr int NMAC = NIT / 4;       // 8 macros (256 fp32 cols each)
constexpr int NKC  = Kdim / 64;     // 256 k-chunks per 128-row block
// swizzled tile: [oct 8][row 128][8 elems] bf16 = 16 KB, contiguous
constexpr int TILE_ELEMS = 8 * 128 * 8;  // 8192

// ws layout (bytes)
constexpr size_t X_SWZ_OFF = 0;
constexpr size_t X_SWZ_SZ  = (size_t)Mdim * Kdim * 2;           // 8 MiB
constexpr size_t PART_OFF  = X_SWZ_OFF + X_SWZ_SZ;
constexpr size_t PART_SZ   = (size_t)KS * Mdim * Ndim * 4;      // 32 MiB
constexpr size_t NEED_FAST = PART_OFF + PART_SZ;                // 40 MiB

// fallback fused gemm (atomic mode) config
constexpr int FMT = 128, FNT = 128, FBK = 32;
constexpr int KS_MID = 16;

// packed fp32x2 -> bf16x2 RNE (v_cvt_pk_bf16_f32 on gfx950)
__device__ __forceinline__ unsigned int cvt2(float lo, float hi) {
  union { __hip_bfloat162 h; unsigned int u; } v;
  v.h = __float22bfloat162_rn(make_float2(lo, hi));
  return v.u;
}

__device__ __forceinline__ void async16(const void* g, void* l) {
  __builtin_amdgcn_global_load_lds(
      (const __attribute__((address_space(1))) void*)g,
      (__attribute__((address_space(3))) void*)l, 16, 0, 0);
}

// ============================================================
// Pass 1: x only -> bf16 fragment-tile swizzle (8 MiB out).
// 128 blocks; same layout the GEMM's A-stager expects.
// ============================================================
__global__ __launch_bounds__(256) void k_prep(const float* __restrict__ x,
                                              unsigned short* __restrict__ x_swz) {
  __shared__ unsigned short sw[4][8][128][8];  // [kc_l][oct][row][8] = 64 KiB
  const int idx = blockIdx.x;     // 0..127
  const int nt = idx >> 6;        // 0..1 (two 128-row tiles of x)
  const int p  = idx & 63;        // 256-k panel
  const int t = threadIdx.x;
  const int r = t >> 1;           // row within 128-tile
  const int h = t & 1;            // half of the 256-k panel

  const float4* s4 = (const float4*)(x + (size_t)(nt * 128 + r) * Kdim + p * 256 + h * 128);
  float4 v[32];
#pragma unroll
  for (int g = 0; g < 32; ++g) v[g] = s4[g];   // 512 B sequential per thread

#pragma unroll
  for (int c = 0; c < 16; ++c) {  // 8-elem chunks: k_local = h*128 + c*8
    const int kc_l = h * 2 + (c >> 3);
    const int oct  = c & 7;
    float4 a = v[2 * c], d = v[2 * c + 1];
    union { short8 s; unsigned int u[4]; } pk;
    pk.u[0] = cvt2(a.x, a.y); pk.u[1] = cvt2(a.z, a.w);
    pk.u[2] = cvt2(d.x, d.y); pk.u[3] = cvt2(d.z, d.w);
    *(short8*)&sw[kc_l][oct][r][0] = pk.s;
  }
  __syncthreads();

  // sequential 64 KiB block store: cells (nt, p*4 .. p*4+3) are adjacent
  const size_t base = ((size_t)nt * NKC + (size_t)p * 4) * TILE_ELEMS;  // in shorts
  const float4* lsrc = (const float4*)&sw[0][0][0][0];
  float4* gdst = (float4*)(x_swz + base);
#pragma unroll
  for (int i = 0; i < 16; ++i) gdst[i * 256 + t] = lsrc[i * 256 + t];
}

// ============================================================
// Pass 2: fused-convert bf16 MFMA GEMM. BM=256 (all of M), BN=128.
// Grid (32 nb, 8 kz) = 256 blocks = 1 block/CU, 512 threads (8 waves).
//   A: x_swz (bf16, swizzled) via global_load_lds width=16, double-buffered.
//   B: e fp32 streamed ONCE from HBM in MACRO bursts of 256 cols:
//      4-thread row-groups read 1 KiB contiguous per row (DRAM page friendly)
//      into v4[16] ONLY (no bf16 stash -> no spills), convert AT WRITE time,
//      dribbling one 64-col chunk per sub-iter into quad-slot ldsB.
//      Write schedule (proven in r2): slot 3 of macro m written at c=0
//      (BEFORE issueMac(m+1) recycles v4); slots 0..2 of macro m+1 written
//      at c=1..3. Every write is barrier-separated from same-slot reads.
// part[z][m][n] = esq_slice(z,n) - 2 * x.e |_kslice(z)
// ============================================================
__global__ __launch_bounds__(512, 2) void k_gemm_f(const unsigned short* __restrict__ x_swz,
                                                   const float* __restrict__ e,
                                                   float* __restrict__ part) {
  __shared__ unsigned short ldsA[2][2][8][128][8];  // [buf][nt][oct][row][8] = 64 KiB
  __shared__ unsigned short ldsB[4][8][128][8];     // [slot][oct][row][8]    = 64 KiB
  __shared__ float esq_sh[128];
  const int t = threadIdx.x;
  const int nb = blockIdx.x;   // 0..31
  const int kz = blockIdx.y;   // 0..7
  const int n0 = nb * 128;
  const int k0 = kz * KC;

  const int wave = t >> 6, lane = t & 63;
  const int wm = (wave & 3) * 64;   // 4-way M split over 256 rows
  const int wn = (wave >> 2) * 64;  // 2-way N split over 128 cols
  const int lcol = lane & 15, quad = lane >> 4;

  // A staging: two x_swz row-tiles (nt=0,1), k-chunks kz*NIT + it
  const unsigned short* A0 = x_swz + ((size_t)(0 * NKC) + kz * NIT) * TILE_ELEMS;
  const unsigned short* A1 = x_swz + ((size_t)(1 * NKC) + kz * NIT) * TILE_ELEMS;

  // B per-thread: row br = t>>2 (0..127), chunk kq = t&3 (64 fp32 cols of macro)
  const int br = t >> 2, kq = t & 3;
  const float* ep = e + (size_t)(n0 + br) * Kdim + k0 + kq * 64;

  float4 v4[16];   // fp32 macro burst (64 floats) -- the ONLY B register state
  float sq = 0.0f;

  auto issueMac = [&](int M) {
    const float4* p4 = (const float4*)(ep + (size_t)M * 256);
#pragma unroll
    for (int g = 0; g < 16; ++g) v4[g] = p4[g];  // 4-thread group: 1 KiB/row burst
  };
  // threads owning chunk w convert v4 -> bf16 and write slot w (once/macro)
  auto writeChunk = [&](int w) {
    if (kq == w) {
#pragma unroll
      for (int o = 0; o < 8; ++o) {
        float4 a = v4[2 * o], b = v4[2 * o + 1];
        sq += a.x * a.x + a.y * a.y + a.z * a.z + a.w * a.w
            + b.x * b.x + b.y * b.y + b.z * b.z + b.w * b.w;
        union { short8 s; unsigned int u[4]; } pk;
        pk.u[0] = cvt2(a.x, a.y); pk.u[1] = cvt2(a.z, a.w);
        pk.u[2] = cvt2(b.x, b.y); pk.u[3] = cvt2(b.z, b.w);
        *(short8*)&ldsB[w][o][br][0] = pk.s;
      }
    }
  };
  auto stageA = [&](int buf, int it) {
    const unsigned short* a0 = A0 + (size_t)it * TILE_ELEMS;
    const unsigned short* a1 = A1 + (size_t)it * TILE_ELEMS;
    unsigned short* d0 = &ldsA[buf][0][0][0][0];
    unsigned short* d1 = &ldsA[buf][1][0][0][0];
#pragma unroll
    for (int j = 0; j < 2; ++j) {
      int cell = j * 512 + t;
      async16(a0 + (size_t)cell * 8, d0 + cell * 8);
      async16(a1 + (size_t)cell * 8, d1 + cell * 8);
    }
  };

  f32x4 acc[4][4] = {};

  // prologue: macro 0 -> v4; write slots 0..2 (chunk 3 written at it=0, c=0)
  issueMac(0);
  stageA(0, 0);
  writeChunk(0); writeChunk(1); writeChunk(2);
  __syncthreads();

#pragma unroll 4
  for (int it = 0; it < NIT; ++it) {
    const int m = it >> 2, c = it & 3, cur = it & 1;
    if (c == 0) {
      writeChunk(3);                               // macro m chunk 3 (v4 still macro m)
      if (m + 1 < NMAC) issueMac(m + 1);           // then recycle v4: 1 KiB/row burst
    }
    if (it + 1 < NIT) stageA(cur ^ 1, it + 1);     // async A into other buffer

    // frags + MFMA (read ldsA[cur], ldsB[slot c])
#pragma unroll
    for (int s = 0; s < 2; ++s) {
      const int oct = s * 4 + quad;
      short8 af[4], bfv[4];
#pragma unroll
      for (int mi = 0; mi < 4; ++mi) {
        const int mr = wm + mi * 16 + lcol;
        af[mi] = *(const short8*)&ldsA[cur][mr >> 7][oct][mr & 127][0];
      }
#pragma unroll
      for (int ni = 0; ni < 4; ++ni)
        bfv[ni] = *(const short8*)&ldsB[c][oct][wn + ni * 16 + lcol][0];
#pragma unroll
      for (int mi = 0; mi < 4; ++mi)
#pragma unroll
        for (int ni = 0; ni < 4; ++ni)
          acc[mi][ni] = __builtin_amdgcn_mfma_f32_16x16x32_bf16(af[mi], bfv[ni], acc[mi][ni], 0, 0, 0);
    }

    if (c > 0 && m + 1 < NMAC) writeChunk(c - 1);  // macro m+1 chunk c-1 from v4
    __syncthreads();  // drains A asyncs (+ mac loads at c==0) + fences ds writes
  }

  // ||e||^2 slice partial: 4 threads per row -> shfl reduce
  sq += __shfl_xor(sq, 1, 64);
  sq += __shfl_xor(sq, 2, 64);
  if (kq == 0) esq_sh[br] = sq;
  __syncthreads();

  // epilogue: C/D layout col=lane&15, row=quad*4+reg
  float* base = part + (size_t)kz * Mdim * Ndim;
#pragma unroll
  for (int ni = 0; ni < 4; ++ni) {
    const int cl = wn + ni * 16 + lcol;
    const float ev = esq_sh[cl];
#pragma unroll
    for (int mi = 0; mi < 4; ++mi)
#pragma unroll
      for (int reg = 0; reg < 4; ++reg) {
        const int row = wm + mi * 16 + quad * 4 + reg;
        base[(size_t)row * Ndim + n0 + cl] = ev - 2.0f * acc[mi][ni][reg];
      }
  }
}

// ============================================================
// Fused select: split-K reduce (compile-time NZ, unrolled) + top-2
// + exact fp32 refine + one-hot write
// ============================================================
template <int NZ>
__global__ __launch_bounds__(256) void k_select_t(const float* __restrict__ part,
                                                  const float* __restrict__ x,
                                                  const float* __restrict__ e,
                                                  float* __restrict__ out) {
  __shared__ float sv1[256], sv2[256];
  __shared__ int   si1[256], si2[256];
  __shared__ float s1[256], s2[256];
  __shared__ int win_sh;
  const int b = blockIdx.x, t = threadIdx.x;

  float v1 = 3.4e38f, v2 = 3.4e38f; int i1 = 0, i2 = 1;
  auto upd = [&](float v, int idx) {
    if (v < v1)      { v2 = v1; i2 = i1; v1 = v; i1 = idx; }
    else if (v < v2) { v2 = v;  i2 = idx; }
  };
#pragma unroll
  for (int i = 0; i < Ndim / 4 / 256; ++i) {
    int q = t + i * 256;  // float4 index over n
    float sx = 0.f, sy = 0.f, sz = 0.f, sw = 0.f;
#pragma unroll
    for (int z = 0; z < NZ; ++z) {
      float4 v = ((const float4*)part)[((size_t)z * Mdim + b) * (Ndim / 4) + q];
      sx += v.x; sy += v.y; sz += v.z; sw += v.w;
    }
    upd(sx, 4 * q + 0); upd(sy, 4 * q + 1); upd(sz, 4 * q + 2); upd(sw, 4 * q + 3);
  }
  sv1[t] = v1; si1[t] = i1; sv2[t] = v2; si2[t] = i2;
  __syncthreads();
  for (int sOff = 128; sOff > 0; sOff >>= 1) {
    if (t < sOff) {
      float bv1 = sv1[t + sOff], bv2 = sv2[t + sOff];
      int   bi1 = si1[t + sOff], bi2 = si2[t + sOff];
      float av1 = sv1[t],        av2 = sv2[t];
      int   ai1 = si1[t],        ai2 = si2[t];
      if (bv1 < av1)      { av2 = av1; ai2 = ai1; av1 = bv1; ai1 = bi1; }
      else if (bv1 < av2) { av2 = bv1; ai2 = bi1; }
      if (bv2 < av2)      { av2 = bv2; ai2 = bi2; }
      sv1[t] = av1; si1[t] = ai1; sv2[t] = av2; si2[t] = ai2;
    }
    __syncthreads();
  }
  const int c1 = si1[0], c2 = si2[0];

  // exact fp32 distances for the two candidates
  const float4* xb = (const float4*)(x + (size_t)b  * Kdim);
  const float4* e1 = (const float4*)(e + (size_t)c1 * Kdim);
  const float4* e2 = (const float4*)(e + (size_t)c2 * Kdim);
  float a1 = 0.f, a2 = 0.f;
#pragma unroll 4
  for (int i = 0; i < Kdim / 4 / 256; ++i) {
    int q = t + i * 256;
    float4 xv  = xb[q];
    float4 ev1 = e1[q];
    float4 ev2 = e2[q];
    a1 += ev1.x * (ev1.x - 2.f * xv.x) + ev1.y * (ev1.y - 2.f * xv.y)
        + ev1.z * (ev1.z - 2.f * xv.z) + ev1.w * (ev1.w - 2.f * xv.w);
    a2 += ev2.x * (ev2.x - 2.f * xv.x) + ev2.y * (ev2.y - 2.f * xv.y)
        + ev2.z * (ev2.z - 2.f * xv.z) + ev2.w * (ev2.w - 2.f * xv.w);
  }
  s1[t] = a1; s2[t] = a2;
  __syncthreads();
  for (int sOff = 128; sOff > 0; sOff >>= 1) {
    if (t < sOff) { s1[t] += s1[t + sOff]; s2[t] += s2[t + sOff]; }
    __syncthreads();
  }
  if (t == 0) {
    float d1 = s1[0], d2 = s2[0];
    win_sh = (d2 < d1 || (d2 == d1 && c2 < c1)) ? c2 : c1;  // np.argmin tie: smaller idx
  }
  __syncthreads();

  const int win = win_sh;
  float* outb = out + (size_t)b * Ndim;
#pragma unroll
  for (int g = 0; g < 4; ++g) {
    int q = g * 256 + t;
    float4 v;
    v.x = (win == 4 * q + 0) ? 1.f : 0.f;
    v.y = (win == 4 * q + 1) ? 1.f : 0.f;
    v.z = (win == 4 * q + 2) ? 1.f : 0.f;
    v.w = (win == 4 * q + 3) ? 1.f : 0.f;
    ((float4*)outb)[q] = v;
  }
}

// ============================================================
// Fallback tier (tiny/no workspace): fused gemm with atomics into out.
// ============================================================
__global__ __launch_bounds__(256) void k_gemm_fused(const float* __restrict__ x,
                                                    const float* __restrict__ e,
                                                    float* __restrict__ dst,
                                                    int ws_mode) {
  __shared__ short lds[2][2][4][128][8];
  __shared__ float esq_part[256];
  __shared__ float esq_sh[128];
  const int t  = threadIdx.x;
  const int n0 = blockIdx.x * FNT;
  const int m0 = blockIdx.y * FMT;
  const int kz = blockIdx.z;
  const int KCF = Kdim / KS_MID;
  const int NITF = KCF / FBK;
  const int k0 = kz * KCF;
  const int r  = t >> 1;
  const int kq = (t & 1) * 16;
  const int g0 = (t & 1) * 2;
  const float* xp = x + (size_t)(m0 + r) * Kdim + k0 + kq;
  const float* ep = e + (size_t)(n0 + r) * Kdim + k0 + kq;
  const int wave = t >> 6, lane = t & 63;
  const int wm = (wave & 1) * 64, wn = (wave >> 1) * 64;
  const int lcol = lane & 15, quad = lane >> 4;

  f32x4 acc[4][4] = {};
  float esq_acc = 0.0f;
  float4 bufA[4], bufB[4];
#pragma unroll
  for (int g = 0; g < 4; ++g) {
    bufA[g] = ((const float4*)xp)[g];
    bufB[g] = ((const float4*)ep)[g];
  }
  auto stagef = [&](int buf) {
    union { short8 s; unsigned int u[4]; } pa0, pa1, pb0, pb1;
    pa0.u[0] = cvt2(bufA[0].x, bufA[0].y); pa0.u[1] = cvt2(bufA[0].z, bufA[0].w);
    pa0.u[2] = cvt2(bufA[1].x, bufA[1].y); pa0.u[3] = cvt2(bufA[1].z, bufA[1].w);
    pa1.u[0] = cvt2(bufA[2].x, bufA[2].y); pa1.u[1] = cvt2(bufA[2].z, bufA[2].w);
    pa1.u[2] = cvt2(bufA[3].x, bufA[3].y); pa1.u[3] = cvt2(bufA[3].z, bufA[3].w);
    pb0.u[0] = cvt2(bufB[0].x, bufB[0].y); pb0.u[1] = cvt2(bufB[0].z, bufB[0].w);
    pb0.u[2] = cvt2(bufB[1].x, bufB[1].y); pb0.u[3] = cvt2(bufB[1].z, bufB[1].w);
    pb1.u[0] = cvt2(bufB[2].x, bufB[2].y); pb1.u[1] = cvt2(bufB[2].z, bufB[2].w);
    pb1.u[2] = cvt2(bufB[3].x, bufB[3].y); pb1.u[3] = cvt2(bufB[3].z, bufB[3].w);
#pragma unroll
    for (int g = 0; g < 4; ++g)
      esq_acc += bufB[g].x * bufB[g].x + bufB[g].y * bufB[g].y
               + bufB[g].z * bufB[g].z + bufB[g].w * bufB[g].w;
    *(short8*)&lds[buf][0][g0    ][r][0] = pa0.s;
    *(short8*)&lds[buf][0][g0 + 1][r][0] = pa1.s;
    *(short8*)&lds[buf][1][g0    ][r][0] = pb0.s;
    *(short8*)&lds[buf][1][g0 + 1][r][0] = pb1.s;
  };
  stagef(0);
  __syncthreads();
  for (int it = 0; it < NITF; ++it) {
    const int cur = it & 1;
    if (it + 1 < NITF) {
      const float* xn = xp + (size_t)(it + 1) * FBK;
      const float* en = ep + (size_t)(it + 1) * FBK;
#pragma unroll
      for (int g = 0; g < 4; ++g) {
        bufA[g] = ((const float4*)xn)[g];
        bufB[g] = ((const float4*)en)[g];
      }
    }
    short8 af[4], bfr[4];
#pragma unroll
    for (int mi = 0; mi < 4; ++mi)
      af[mi] = *(const short8*)&lds[cur][0][quad][wm + mi * 16 + lcol][0];
#pragma unroll
    for (int ni = 0; ni < 4; ++ni)
      bfr[ni] = *(const short8*)&lds[cur][1][quad][wn + ni * 16 + lcol][0];
#pragma unroll
    for (int mi = 0; mi < 4; ++mi)
#pragma unroll
      for (int ni = 0; ni < 4; ++ni)
        acc[mi][ni] = __builtin_amdgcn_mfma_f32_16x16x32_bf16(af[mi], bfr[ni], acc[mi][ni], 0, 0, 0);
    if (it + 1 < NITF) {
      stagef(cur ^ 1);
      __syncthreads();
    }
  }
  esq_part[t] = esq_acc;
  __syncthreads();
  if (t < 128) esq_sh[t] = esq_part[2 * t] + esq_part[2 * t + 1];
  __syncthreads();
  if (ws_mode) {
    float* base = dst + (size_t)kz * Mdim * Ndim;
#pragma unroll
    for (int mi = 0; mi < 4; ++mi)
#pragma unroll
      for (int ni = 0; ni < 4; ++ni)
#pragma unroll
        for (int reg = 0; reg < 4; ++reg) {
          int row = m0 + wm + mi * 16 + quad * 4 + reg;
          int cl  = wn + ni * 16 + lcol;
          base[(size_t)row * Ndim + n0 + cl] = esq_sh[cl] - 2.0f * acc[mi][ni][reg];
        }
  } else {
#pragma unroll
    for (int mi = 0; mi < 4; ++mi)
#pragma unroll
      for (int ni = 0; ni < 4; ++ni)
#pragma unroll
        for (int reg = 0; reg < 4; ++reg) {
          int row = m0 + wm + mi * 16 + quad * 4 + reg;
          int cl  = wn + ni * 16 + lcol;
          atomicAdd(&dst[(size_t)row * Ndim + n0 + cl], esq_sh[cl] - 2.0f * acc[mi][ni][reg]);
        }
  }
}

extern "C" void kernel_launch(void* const* d_in, const int* in_sizes, int n_in,
                              void* d_out, int out_size, void* d_ws, size_t ws_size,
                              hipStream_t stream) {
  (void)in_sizes; (void)n_in; (void)out_size;
  const float* x = (const float*)d_in[0];  // [256, 16384] fp32
  const float* e = (const float*)d_in[1];  // [4096, 16384] fp32
  float* out = (float*)d_out;
  char* ws = (char*)d_ws;

  if (ws_size >= NEED_FAST) {
    unsigned short* x_swz = (unsigned short*)(ws + X_SWZ_OFF);
    float* part = (float*)(ws + PART_OFF);
    hipLaunchKernelGGL(k_prep, dim3(128), dim3(256), 0, stream, x, x_swz);
    hipLaunchKernelGGL(k_gemm_f, dim3(Ndim / 128, KS), dim3(512), 0, stream,
                       x_swz, e, part);
    hipLaunchKernelGGL(k_select_t<KS>, dim3(Mdim), dim3(256), 0, stream, part, x, e, out);
  } else if (ws_size >= (size_t)KS_MID * Mdim * Ndim * 4) {
    float* part = (float*)ws;
    hipLaunchKernelGGL(k_gemm_fused, dim3(Ndim / FNT, Mdim / FMT, KS_MID), dim3(256), 0, stream,
                       x, e, part, 1);
    hipLaunchKernelGGL(k_select_t<KS_MID>, dim3(Mdim), dim3(256), 0, stream, part, x, e, out);
  } else {
    hipMemsetAsync(d_out, 0, (size_t)Mdim * Ndim * sizeof(float), stream);
    hipLaunchKernelGGL(k_gemm_fused, dim3(Ndim / FNT, Mdim / FMT, KS_MID), dim3(256), 0, stream,
                       x, e, out, 0);
    hipLaunchKernelGGL(k_select_t<1>, dim3(Mdim), dim3(256), 0, stream, out, x, e, out);
  }
}

// Round 4
// 426.123 us; speedup vs baseline: 1.0923x; 1.0399x over previous
//
#include <hip/hip_runtime.h>
#include <hip/hip_bf16.h>
#include <stdint.h>

// Problem dims (fixed by the reference)
constexpr int Mdim = 256;    // batch
constexpr int Ndim = 4096;   // codes E
constexpr int Kdim = 16384;  // EMB

typedef __attribute__((ext_vector_type(8))) short short8;  // 8 x bf16 (4 VGPR)
typedef __attribute__((ext_vector_type(4))) float f32x4;

// ---------- fused-convert GEMM config (fast path) ----------
constexpr int KS   = 8;             // split-K
constexpr int KC   = Kdim / KS;     // 2048 k per block
constexpr int BKs  = 32;            // K per sub-iteration
constexpr int NITs = KC / BKs;      // 64 sub-iterations
constexpr int NKC  = Kdim / 64;     // 256 64-k chunks per 128-row x tile
// x_swz tile: [oct 8][row 128][8 elems] bf16 = 16 KB, contiguous per (nt, chunk)
constexpr int TILE_ELEMS = 8 * 128 * 8;  // 8192 shorts

// ws layout (bytes)
constexpr size_t X_SWZ_OFF = 0;
constexpr size_t X_SWZ_SZ  = (size_t)Mdim * Kdim * 2;           // 8 MiB
constexpr size_t PART_OFF  = X_SWZ_OFF + X_SWZ_SZ;
constexpr size_t PART_SZ   = (size_t)KS * Mdim * Ndim * 4;      // 32 MiB
constexpr size_t NEED_FAST = PART_OFF + PART_SZ;                // 40 MiB

// fallback fused gemm (atomic mode) config
constexpr int FMT = 128, FNT = 128, FBK = 32;
constexpr int KS_MID = 16;

// packed fp32x2 -> bf16x2 RNE (v_cvt_pk_bf16_f32 on gfx950)
__device__ __forceinline__ unsigned int cvt2(float lo, float hi) {
  union { __hip_bfloat162 h; unsigned int u; } v;
  v.h = __float22bfloat162_rn(make_float2(lo, hi));
  return v.u;
}

__device__ __forceinline__ void async16(const void* g, void* l) {
  __builtin_amdgcn_global_load_lds(
      (const __attribute__((address_space(1))) void*)g,
      (__attribute__((address_space(3))) void*)l, 16, 0, 0);
}

// ============================================================
// Pass 1: x only -> bf16 fragment-tile swizzle (8 MiB out).
// 128 blocks; same layout the GEMM's A-stager expects.
// ============================================================
__global__ __launch_bounds__(256) void k_prep(const float* __restrict__ x,
                                              unsigned short* __restrict__ x_swz) {
  __shared__ unsigned short sw[4][8][128][8];  // [kc_l][oct][row][8] = 64 KiB
  const int idx = blockIdx.x;     // 0..127
  const int nt = idx >> 6;        // 0..1 (two 128-row tiles of x)
  const int p  = idx & 63;        // 256-k panel
  const int t = threadIdx.x;
  const int r = t >> 1;           // row within 128-tile
  const int h = t & 1;            // half of the 256-k panel

  const float4* s4 = (const float4*)(x + (size_t)(nt * 128 + r) * Kdim + p * 256 + h * 128);
  float4 v[32];
#pragma unroll
  for (int g = 0; g < 32; ++g) v[g] = s4[g];   // 512 B sequential per thread

#pragma unroll
  for (int c = 0; c < 16; ++c) {  // 8-elem chunks: k_local = h*128 + c*8
    const int kc_l = h * 2 + (c >> 3);
    const int oct  = c & 7;
    float4 a = v[2 * c], d = v[2 * c + 1];
    union { short8 s; unsigned int u[4]; } pk;
    pk.u[0] = cvt2(a.x, a.y); pk.u[1] = cvt2(a.z, a.w);
    pk.u[2] = cvt2(d.x, d.y); pk.u[3] = cvt2(d.z, d.w);
    *(short8*)&sw[kc_l][oct][r][0] = pk.s;
  }
  __syncthreads();

  // sequential 64 KiB block store: cells (nt, p*4 .. p*4+3) are adjacent
  const size_t base = ((size_t)nt * NKC + (size_t)p * 4) * TILE_ELEMS;  // in shorts
  const float4* lsrc = (const float4*)&sw[0][0][0][0];
  float4* gdst = (float4*)(x_swz + base);
#pragma unroll
  for (int i = 0; i < 16; ++i) gdst[i * 256 + t] = lsrc[i * 256 + t];
}

// ============================================================
// Pass 2: fused-convert bf16 MFMA GEMM. BM=256, BN=64, BK=32, KS=8.
// Grid (64 nb, 8 kz) = 512 blocks = 2 blocks/CU (the r0-proven occupancy
// that hides per-sub-iter vmcnt(0) barrier drains via cross-block waves).
// 512 threads (8 waves), LDS ~41 KiB, VGPR capped at 128 (16 waves/CU).
//   A: x_swz (bf16, swizzled) via global_load_lds width=16, double-buffered.
//   B: e fp32 streamed ONCE from HBM (1 float4/thread/sub-iter) -> cvt at
//      write time -> double-buffered ldsB. ||e||^2 on the fly.
// part[z][m][n] = esq_slice(z,n) - 2 * x.e |_kslice(z)
// ============================================================
__global__ __launch_bounds__(512, 4) void k_gemm_f(const unsigned short* __restrict__ x_swz,
                                                   const float* __restrict__ e,
                                                   float* __restrict__ part) {
  __shared__ unsigned short ldsA[2][2][4][128][8];  // [buf][nt][oct][row][8] = 32 KiB
  __shared__ unsigned short ldsB[2][4][64][8];      // [buf][oct][row][8]     =  8 KiB
  __shared__ float esq_sh[64];
  const int t = threadIdx.x;
  const int nb = blockIdx.x;   // 0..63
  const int kz = blockIdx.y;   // 0..7
  const int n0 = nb * 64;
  const int k0 = kz * KC;

  const int wave = t >> 6, lane = t & 63;
  const int wm = (wave & 3) * 64;   // 4-way M split over 256 rows
  const int wn = (wave >> 2) * 32;  // 2-way N split over 64 cols
  const int lcol = lane & 15, quad = lane >> 4;

  // B per-thread: row br = t>>3 (0..63), group bg = t&7 (4 cols = 16 B)
  const int br = t >> 3, bg = t & 7;
  const float* ep = e + (size_t)(n0 + br) * Kdim + k0 + bg * 4;

  float4 bv;       // single-float4 B prefetch
  float sq = 0.0f;

  auto loadB = [&](int it) { bv = *(const float4*)(ep + (size_t)it * BKs); };
  auto writeB = [&](int buf) {
    sq += bv.x * bv.x + bv.y * bv.y + bv.z * bv.z + bv.w * bv.w;
    uint2 pk;
    pk.x = cvt2(bv.x, bv.y); pk.y = cvt2(bv.z, bv.w);
    *(uint2*)&ldsB[buf][bg >> 1][br][(bg & 1) * 4] = pk;  // 8 B aligned store
  };
  // sub-iter it: 64-k chunk = kz*32 + (it>>1), half (it&1) = octs [h*4, h*4+4)
  auto stageA = [&](int buf, int it) {
    const unsigned short* src = x_swz + ((size_t)(kz * 32 + (it >> 1))) * TILE_ELEMS
                              + (size_t)(it & 1) * 4096;
#pragma unroll
    for (int nt = 0; nt < 2; ++nt)
      async16(src + (size_t)nt * NKC * TILE_ELEMS + (size_t)t * 8,
              &ldsA[buf][nt][0][0][0] + t * 8);   // 8 KiB contiguous per nt
  };

  f32x4 acc[4][2] = {};
  loadB(0);
  stageA(0, 0);
  writeB(0);
  __syncthreads();  // buf0 ready (A asyncs drained + B writes fenced)

#pragma unroll 2
  for (int it = 0; it < NITs; ++it) {
    const int cur = it & 1;
    const bool pre = (it + 1 < NITs);
    if (pre) { loadB(it + 1); stageA(cur ^ 1, it + 1); }

    short8 af[4], bf[2];
#pragma unroll
    for (int mi = 0; mi < 4; ++mi) {
      const int mr = wm + mi * 16 + lcol;
      af[mi] = *(const short8*)&ldsA[cur][mr >> 7][quad][mr & 127][0];
    }
#pragma unroll
    for (int ni = 0; ni < 2; ++ni)
      bf[ni] = *(const short8*)&ldsB[cur][quad][wn + ni * 16 + lcol][0];
#pragma unroll
    for (int mi = 0; mi < 4; ++mi)
#pragma unroll
      for (int ni = 0; ni < 2; ++ni)
        acc[mi][ni] = __builtin_amdgcn_mfma_f32_16x16x32_bf16(af[mi], bf[ni], acc[mi][ni], 0, 0, 0);

    if (pre) writeB(cur ^ 1);   // other buffer: no hazard with cur reads
    __syncthreads();            // drains A asyncs + fences B writes
  }

  // ||e||^2 slice partial: 8 threads per row (low 3 lane bits) -> shfl reduce
  sq += __shfl_xor(sq, 1, 64);
  sq += __shfl_xor(sq, 2, 64);
  sq += __shfl_xor(sq, 4, 64);
  if (bg == 0) esq_sh[br] = sq;
  __syncthreads();

  // epilogue: C/D layout col=lane&15, row=quad*4+reg
  float* base = part + (size_t)kz * Mdim * Ndim;
#pragma unroll
  for (int ni = 0; ni < 2; ++ni) {
    const int cl = wn + ni * 16 + lcol;
    const float ev = esq_sh[cl];
#pragma unroll
    for (int mi = 0; mi < 4; ++mi)
#pragma unroll
      for (int reg = 0; reg < 4; ++reg) {
        const int row = wm + mi * 16 + quad * 4 + reg;
        base[(size_t)row * Ndim + n0 + cl] = ev - 2.0f * acc[mi][ni][reg];
      }
  }
}

// ============================================================
// Fused select: split-K reduce (compile-time NZ, unrolled) + top-2
// + exact fp32 refine + one-hot write
// ============================================================
template <int NZ>
__global__ __launch_bounds__(256) void k_select_t(const float* __restrict__ part,
                                                  const float* __restrict__ x,
                                                  const float* __restrict__ e,
                                                  float* __restrict__ out) {
  __shared__ float sv1[256], sv2[256];
  __shared__ int   si1[256], si2[256];
  __shared__ float s1[256], s2[256];
  __shared__ int win_sh;
  const int b = blockIdx.x, t = threadIdx.x;

  float v1 = 3.4e38f, v2 = 3.4e38f; int i1 = 0, i2 = 1;
  auto upd = [&](float v, int idx) {
    if (v < v1)      { v2 = v1; i2 = i1; v1 = v; i1 = idx; }
    else if (v < v2) { v2 = v;  i2 = idx; }
  };
#pragma unroll
  for (int i = 0; i < Ndim / 4 / 256; ++i) {
    int q = t + i * 256;  // float4 index over n
    float sx = 0.f, sy = 0.f, sz = 0.f, sw = 0.f;
#pragma unroll
    for (int z = 0; z < NZ; ++z) {
      float4 v = ((const float4*)part)[((size_t)z * Mdim + b) * (Ndim / 4) + q];
      sx += v.x; sy += v.y; sz += v.z; sw += v.w;
    }
    upd(sx, 4 * q + 0); upd(sy, 4 * q + 1); upd(sz, 4 * q + 2); upd(sw, 4 * q + 3);
  }
  sv1[t] = v1; si1[t] = i1; sv2[t] = v2; si2[t] = i2;
  __syncthreads();
  for (int sOff = 128; sOff > 0; sOff >>= 1) {
    if (t < sOff) {
      float bv1 = sv1[t + sOff], bv2 = sv2[t + sOff];
      int   bi1 = si1[t + sOff], bi2 = si2[t + sOff];
      float av1 = sv1[t],        av2 = sv2[t];
      int   ai1 = si1[t],        ai2 = si2[t];
      if (bv1 < av1)      { av2 = av1; ai2 = ai1; av1 = bv1; ai1 = bi1; }
      else if (bv1 < av2) { av2 = bv1; ai2 = bi1; }
      if (bv2 < av2)      { av2 = bv2; ai2 = bi2; }
      sv1[t] = av1; si1[t] = ai1; sv2[t] = av2; si2[t] = ai2;
    }
    __syncthreads();
  }
  const int c1 = si1[0], c2 = si2[0];

  // exact fp32 distances for the two candidates
  const float4* xb = (const float4*)(x + (size_t)b  * Kdim);
  const float4* e1 = (const float4*)(e + (size_t)c1 * Kdim);
  const float4* e2 = (const float4*)(e + (size_t)c2 * Kdim);
  float a1 = 0.f, a2 = 0.f;
#pragma unroll 4
  for (int i = 0; i < Kdim / 4 / 256; ++i) {
    int q = t + i * 256;
    float4 xv  = xb[q];
    float4 ev1 = e1[q];
    float4 ev2 = e2[q];
    a1 += ev1.x * (ev1.x - 2.f * xv.x) + ev1.y * (ev1.y - 2.f * xv.y)
        + ev1.z * (ev1.z - 2.f * xv.z) + ev1.w * (ev1.w - 2.f * xv.w);
    a2 += ev2.x * (ev2.x - 2.f * xv.x) + ev2.y * (ev2.y - 2.f * xv.y)
        + ev2.z * (ev2.z - 2.f * xv.z) + ev2.w * (ev2.w - 2.f * xv.w);
  }
  s1[t] = a1; s2[t] = a2;
  __syncthreads();
  for (int sOff = 128; sOff > 0; sOff >>= 1) {
    if (t < sOff) { s1[t] += s1[t + sOff]; s2[t] += s2[t + sOff]; }
    __syncthreads();
  }
  if (t == 0) {
    float d1 = s1[0], d2 = s2[0];
    win_sh = (d2 < d1 || (d2 == d1 && c2 < c1)) ? c2 : c1;  // np.argmin tie: smaller idx
  }
  __syncthreads();

  const int win = win_sh;
  float* outb = out + (size_t)b * Ndim;
#pragma unroll
  for (int g = 0; g < 4; ++g) {
    int q = g * 256 + t;
    float4 v;
    v.x = (win == 4 * q + 0) ? 1.f : 0.f;
    v.y = (win == 4 * q + 1) ? 1.f : 0.f;
    v.z = (win == 4 * q + 2) ? 1.f : 0.f;
    v.w = (win == 4 * q + 3) ? 1.f : 0.f;
    ((float4*)outb)[q] = v;
  }
}

// ============================================================
// Fallback tier (tiny/no workspace): fused gemm with atomics into out.
// ============================================================
__global__ __launch_bounds__(256) void k_gemm_fused(const float* __restrict__ x,
                                                    const float* __restrict__ e,
                                                    float* __restrict__ dst,
                                                    int ws_mode) {
  __shared__ short lds[2][2][4][128][8];
  __shared__ float esq_part[256];
  __shared__ float esq_sh[128];
  const int t  = threadIdx.x;
  const int n0 = blockIdx.x * FNT;
  const int m0 = blockIdx.y * FMT;
  const int kz = blockIdx.z;
  const int KCF = Kdim / KS_MID;
  const int NITF = KCF / FBK;
  const int k0 = kz * KCF;
  const int r  = t >> 1;
  const int kq = (t & 1) * 16;
  const int g0 = (t & 1) * 2;
  const float* xp = x + (size_t)(m0 + r) * Kdim + k0 + kq;
  const float* ep = e + (size_t)(n0 + r) * Kdim + k0 + kq;
  const int wave = t >> 6, lane = t & 63;
  const int wm = (wave & 1) * 64, wn = (wave >> 1) * 64;
  const int lcol = lane & 15, quad = lane >> 4;

  f32x4 acc[4][4] = {};
  float esq_acc = 0.0f;
  float4 bufA[4], bufB[4];
#pragma unroll
  for (int g = 0; g < 4; ++g) {
    bufA[g] = ((const float4*)xp)[g];
    bufB[g] = ((const float4*)ep)[g];
  }
  auto stagef = [&](int buf) {
    union { short8 s; unsigned int u[4]; } pa0, pa1, pb0, pb1;
    pa0.u[0] = cvt2(bufA[0].x, bufA[0].y); pa0.u[1] = cvt2(bufA[0].z, bufA[0].w);
    pa0.u[2] = cvt2(bufA[1].x, bufA[1].y); pa0.u[3] = cvt2(bufA[1].z, bufA[1].w);
    pa1.u[0] = cvt2(bufA[2].x, bufA[2].y); pa1.u[1] = cvt2(bufA[2].z, bufA[2].w);
    pa1.u[2] = cvt2(bufA[3].x, bufA[3].y); pa1.u[3] = cvt2(bufA[3].z, bufA[3].w);
    pb0.u[0] = cvt2(bufB[0].x, bufB[0].y); pb0.u[1] = cvt2(bufB[0].z, bufB[0].w);
    pb0.u[2] = cvt2(bufB[1].x, bufB[1].y); pb0.u[3] = cvt2(bufB[1].z, bufB[1].w);
    pb1.u[0] = cvt2(bufB[2].x, bufB[2].y); pb1.u[1] = cvt2(bufB[2].z, bufB[2].w);
    pb1.u[2] = cvt2(bufB[3].x, bufB[3].y); pb1.u[3] = cvt2(bufB[3].z, bufB[3].w);
#pragma unroll
    for (int g = 0; g < 4; ++g)
      esq_acc += bufB[g].x * bufB[g].x + bufB[g].y * bufB[g].y
               + bufB[g].z * bufB[g].z + bufB[g].w * bufB[g].w;
    *(short8*)&lds[buf][0][g0    ][r][0] = pa0.s;
    *(short8*)&lds[buf][0][g0 + 1][r][0] = pa1.s;
    *(short8*)&lds[buf][1][g0    ][r][0] = pb0.s;
    *(short8*)&lds[buf][1][g0 + 1][r][0] = pb1.s;
  };
  stagef(0);
  __syncthreads();
  for (int it = 0; it < NITF; ++it) {
    const int cur = it & 1;
    if (it + 1 < NITF) {
      const float* xn = xp + (size_t)(it + 1) * FBK;
      const float* en = ep + (size_t)(it + 1) * FBK;
#pragma unroll
      for (int g = 0; g < 4; ++g) {
        bufA[g] = ((const float4*)xn)[g];
        bufB[g] = ((const float4*)en)[g];
      }
    }
    short8 af[4], bfr[4];
#pragma unroll
    for (int mi = 0; mi < 4; ++mi)
      af[mi] = *(const short8*)&lds[cur][0][quad][wm + mi * 16 + lcol][0];
#pragma unroll
    for (int ni = 0; ni < 4; ++ni)
      bfr[ni] = *(const short8*)&lds[cur][1][quad][wn + ni * 16 + lcol][0];
#pragma unroll
    for (int mi = 0; mi < 4; ++mi)
#pragma unroll
      for (int ni = 0; ni < 4; ++ni)
        acc[mi][ni] = __builtin_amdgcn_mfma_f32_16x16x32_bf16(af[mi], bfr[ni], acc[mi][ni], 0, 0, 0);
    if (it + 1 < NITF) {
      stagef(cur ^ 1);
      __syncthreads();
    }
  }
  esq_part[t] = esq_acc;
  __syncthreads();
  if (t < 128) esq_sh[t] = esq_part[2 * t] + esq_part[2 * t + 1];
  __syncthreads();
  if (ws_mode) {
    float* base = dst + (size_t)kz * Mdim * Ndim;
#pragma unroll
    for (int mi = 0; mi < 4; ++mi)
#pragma unroll
      for (int ni = 0; ni < 4; ++ni)
#pragma unroll
        for (int reg = 0; reg < 4; ++reg) {
          int row = m0 + wm + mi * 16 + quad * 4 + reg;
          int cl  = wn + ni * 16 + lcol;
          base[(size_t)row * Ndim + n0 + cl] = esq_sh[cl] - 2.0f * acc[mi][ni][reg];
        }
  } else {
#pragma unroll
    for (int mi = 0; mi < 4; ++mi)
#pragma unroll
      for (int ni = 0; ni < 4; ++ni)
#pragma unroll
        for (int reg = 0; reg < 4; ++reg) {
          int row = m0 + wm + mi * 16 + quad * 4 + reg;
          int cl  = wn + ni * 16 + lcol;
          atomicAdd(&dst[(size_t)row * Ndim + n0 + cl], esq_sh[cl] - 2.0f * acc[mi][ni][reg]);
        }
  }
}

extern "C" void kernel_launch(void* const* d_in, const int* in_sizes, int n_in,
                              void* d_out, int out_size, void* d_ws, size_t ws_size,
                              hipStream_t stream) {
  (void)in_sizes; (void)n_in; (void)out_size;
  const float* x = (const float*)d_in[0];  // [256, 16384] fp32
  const float* e = (const float*)d_in[1];  // [4096, 16384] fp32
  float* out = (float*)d_out;
  char* ws = (char*)d_ws;

  if (ws_size >= NEED_FAST) {
    unsigned short* x_swz = (unsigned short*)(ws + X_SWZ_OFF);
    float* part = (float*)(ws + PART_OFF);
    hipLaunchKernelGGL(k_prep, dim3(128), dim3(256), 0, stream, x, x_swz);
    hipLaunchKernelGGL(k_gemm_f, dim3(Ndim / 64, KS), dim3(512), 0, stream,
                       x_swz, e, part);
    hipLaunchKernelGGL(k_select_t<KS>, dim3(Mdim), dim3(256), 0, stream, part, x, e, out);
  } else if (ws_size >= (size_t)KS_MID * Mdim * Ndim * 4) {
    float* part = (float*)ws;
    hipLaunchKernelGGL(k_gemm_fused, dim3(Ndim / FNT, Mdim / FMT, KS_MID), dim3(256), 0, stream,
                       x, e, part, 1);
    hipLaunchKernelGGL(k_select_t<KS_MID>, dim3(Mdim), dim3(256), 0, stream, part, x, e, out);
  } else {
    hipMemsetAsync(d_out, 0, (size_t)Mdim * Ndim * sizeof(float), stream);
    hipLaunchKernelGGL(k_gemm_fused, dim3(Ndim / FNT, Mdim / FMT, KS_MID), dim3(256), 0, stream,
                       x, e, out, 0);
    hipLaunchKernelGGL(k_select_t<1>, dim3(Mdim), dim3(256), 0, stream, out, x, e, out);
  }
}

// Round 5
// 422.770 us; speedup vs baseline: 1.1009x; 1.0079x over previous
//
#include <hip/hip_runtime.h>
#include <hip/hip_bf16.h>
#include <stdint.h>

// Problem dims (fixed by the reference)
constexpr int Mdim = 256;    // batch
constexpr int Ndim = 4096;   // codes E
constexpr int Kdim = 16384;  // EMB

typedef __attribute__((ext_vector_type(8))) short short8;  // 8 x bf16 (4 VGPR)
typedef __attribute__((ext_vector_type(4))) float f32x4;

// ---------- fused-convert GEMM config (fast path) ----------
constexpr int KS   = 8;             // split-K
constexpr int KC   = Kdim / KS;     // 2048 k per block
constexpr int BKg  = 64;            // K per sub-iteration
constexpr int NITg = KC / BKg;      // 32 sub-iterations
constexpr int NKC  = Kdim / 64;     // 256 64-k chunks per 128-row x tile
// x_swz tile: [oct 8][row 128][8 elems] bf16 = 16 KB, contiguous per (nt, chunk)
constexpr int TILE_ELEMS = 8 * 128 * 8;  // 8192 shorts

// ws layout (bytes)
constexpr size_t X_SWZ_OFF = 0;
constexpr size_t X_SWZ_SZ  = (size_t)Mdim * Kdim * 2;           // 8 MiB
constexpr size_t PART_OFF  = X_SWZ_OFF + X_SWZ_SZ;
constexpr size_t PART_SZ   = (size_t)KS * Mdim * Ndim * 4;      // 32 MiB
constexpr size_t NEED_FAST = PART_OFF + PART_SZ;                // 40 MiB

// fallback fused gemm (atomic mode) config
constexpr int FMT = 128, FNT = 128, FBK = 32;
constexpr int KS_MID = 16;

// packed fp32x2 -> bf16x2 RNE (v_cvt_pk_bf16_f32 on gfx950)
__device__ __forceinline__ unsigned int cvt2(float lo, float hi) {
  union { __hip_bfloat162 h; unsigned int u; } v;
  v.h = __float22bfloat162_rn(make_float2(lo, hi));
  return v.u;
}

__device__ __forceinline__ void async16(const void* g, void* l) {
  __builtin_amdgcn_global_load_lds(
      (const __attribute__((address_space(1))) void*)g,
      (__attribute__((address_space(3))) void*)l, 16, 0, 0);
}

// ============================================================
// Pass 1: x only -> bf16 fragment-tile swizzle (8 MiB out).
// 256 blocks (full chip); 128-row x 128-k half-panel per block.
// ============================================================
__global__ __launch_bounds__(256) void k_prep(const float* __restrict__ x,
                                              unsigned short* __restrict__ x_swz) {
  __shared__ unsigned short sw[2][8][128][8];  // [kc_l][oct][row][8] = 32 KiB
  const int idx = blockIdx.x;     // 0..255
  const int nt = idx >> 7;        // 0..1 (two 128-row tiles of x)
  const int p  = idx & 127;       // 128-k panel
  const int t = threadIdx.x;
  const int r = t >> 1;           // row within 128-tile
  const int h = t & 1;            // half of the 128-k panel (one 64-k chunk)

  const float4* s4 = (const float4*)(x + (size_t)(nt * 128 + r) * Kdim + p * 128 + h * 64);
  float4 v[16];
#pragma unroll
  for (int g = 0; g < 16; ++g) v[g] = s4[g];   // 256 B sequential per thread

#pragma unroll
  for (int c = 0; c < 8; ++c) {  // oct c: k_local = h*64 + c*8
    float4 a = v[2 * c], d = v[2 * c + 1];
    union { short8 s; unsigned int u[4]; } pk;
    pk.u[0] = cvt2(a.x, a.y); pk.u[1] = cvt2(a.z, a.w);
    pk.u[2] = cvt2(d.x, d.y); pk.u[3] = cvt2(d.z, d.w);
    *(short8*)&sw[h][c][r][0] = pk.s;
  }
  __syncthreads();

  // sequential 32 KiB block store: chunks (p*2, p*2+1) are adjacent
  const size_t base = ((size_t)nt * NKC + (size_t)p * 2) * TILE_ELEMS;  // in shorts
  const float4* lsrc = (const float4*)&sw[0][0][0][0];
  float4* gdst = (float4*)(x_swz + base);
#pragma unroll
  for (int i = 0; i < 8; ++i) gdst[i * 256 + t] = lsrc[i * 256 + t];
}

// ============================================================
// Pass 2: fused-convert bf16 MFMA GEMM. BM=256, BN=64, BK=64, KS=8.
// Grid (64 nb, 8 kz) = 512 blocks = 2 blocks/CU (LDS = exactly 80 KiB:
// 2 x 81920 = the full 160 KiB pool; r2 showed LDS alloc is exact).
// 512 threads (8 waves); 32 barriers per K-slice (half of round 4).
//   A: x_swz (bf16, swizzled) via global_load_lds width=16, double-buffered.
//   B: e fp32 streamed ONCE from HBM (2 x float4 = 32 B contig per thread
//      per sub-iter) -> cvt at write time -> double-buffered ldsB.
//   ||e||^2 on the fly; esq staging overlaid on ldsB after the K-loop.
// part[z][m][n] = esq_slice(z,n) - 2 * x.e |_kslice(z)
// ============================================================
__global__ __launch_bounds__(512, 4) void k_gemm_f(const unsigned short* __restrict__ x_swz,
                                                   const float* __restrict__ e,
                                                   float* __restrict__ part) {
  __shared__ unsigned short ldsA[2][2][8][128][8];  // [buf][nt][oct][row][8] = 64 KiB
  __shared__ unsigned short ldsB[2][8][64][8];      // [buf][oct][row][8]     = 16 KiB
  const int t = threadIdx.x;
  const int nb = blockIdx.x;   // 0..63
  const int kz = blockIdx.y;   // 0..7
  const int n0 = nb * 64;
  const int k0 = kz * KC;

  const int wave = t >> 6, lane = t & 63;
  const int wm = (wave & 3) * 64;   // 4-way M split over 256 rows
  const int wn = (wave >> 2) * 32;  // 2-way N split over 64 cols
  const int lcol = lane & 15, quad = lane >> 4;

  // B per-thread: row br = t>>3 (0..63), oct bg = t&7 (8 cols = 32 B)
  const int br = t >> 3, bg = t & 7;
  const float* ep = e + (size_t)(n0 + br) * Kdim + k0 + bg * 8;

  float4 bv0, bv1;  // 32 B B prefetch
  float sq = 0.0f;

  auto loadB = [&](int it) {
    const float4* p4 = (const float4*)(ep + (size_t)it * BKg);
    bv0 = p4[0]; bv1 = p4[1];
  };
  auto writeB = [&](int buf) {
    sq += bv0.x * bv0.x + bv0.y * bv0.y + bv0.z * bv0.z + bv0.w * bv0.w
        + bv1.x * bv1.x + bv1.y * bv1.y + bv1.z * bv1.z + bv1.w * bv1.w;
    union { short8 s; unsigned int u[4]; } pk;
    pk.u[0] = cvt2(bv0.x, bv0.y); pk.u[1] = cvt2(bv0.z, bv0.w);
    pk.u[2] = cvt2(bv1.x, bv1.y); pk.u[3] = cvt2(bv1.z, bv1.w);
    *(short8*)&ldsB[buf][bg][br][0] = pk.s;  // one 16 B store, oct bg complete
  };
  // sub-iter it: stage full 64-k chunk kz*32+it for both x row-tiles
  auto stageA = [&](int buf, int it) {
    const unsigned short* src = x_swz + (size_t)(kz * NITg + it) * TILE_ELEMS;
#pragma unroll
    for (int nt = 0; nt < 2; ++nt)
#pragma unroll
      for (int j = 0; j < 2; ++j) {
        const int cell = j * 512 + t;
        async16(src + (size_t)nt * NKC * TILE_ELEMS + (size_t)cell * 8,
                &ldsA[buf][nt][0][0][0] + (size_t)cell * 8);
      }
  };

  f32x4 acc[4][2] = {};
  loadB(0);
  stageA(0, 0);
  writeB(0);
  __syncthreads();  // buf0 ready (A asyncs drained + B writes fenced)

#pragma unroll 2
  for (int it = 0; it < NITg; ++it) {
    const int cur = it & 1;
    const bool pre = (it + 1 < NITg);
    if (pre) { loadB(it + 1); stageA(cur ^ 1, it + 1); }

#pragma unroll
    for (int s = 0; s < 2; ++s) {          // per-s frag loading: VGPR-lean
      const int oct = s * 4 + quad;
      short8 af[4], bf[2];
#pragma unroll
      for (int mi = 0; mi < 4; ++mi) {
        const int mr = wm + mi * 16 + lcol;
        af[mi] = *(const short8*)&ldsA[cur][mr >> 7][oct][mr & 127][0];
      }
#pragma unroll
      for (int ni = 0; ni < 2; ++ni)
        bf[ni] = *(const short8*)&ldsB[cur][oct][wn + ni * 16 + lcol][0];
#pragma unroll
      for (int mi = 0; mi < 4; ++mi)
#pragma unroll
        for (int ni = 0; ni < 2; ++ni)
          acc[mi][ni] = __builtin_amdgcn_mfma_f32_16x16x32_bf16(af[mi], bf[ni], acc[mi][ni], 0, 0, 0);
    }

    if (pre) writeB(cur ^ 1);   // other buffer: no hazard with cur reads
    __syncthreads();            // drains A asyncs + fences B writes
  }

  // ||e||^2 slice partial: 8 threads per row (low 3 lane bits) -> shfl reduce.
  // esq staging overlaid on ldsB (free after the loop's final barrier).
  sq += __shfl_xor(sq, 1, 64);
  sq += __shfl_xor(sq, 2, 64);
  sq += __shfl_xor(sq, 4, 64);
  float* esqp = (float*)&ldsB[0][0][0][0];
  if (bg == 0) esqp[br] = sq;
  __syncthreads();

  // epilogue: C/D layout col=lane&15, row=quad*4+reg
  float* base = part + (size_t)kz * Mdim * Ndim;
#pragma unroll
  for (int ni = 0; ni < 2; ++ni) {
    const int cl = wn + ni * 16 + lcol;
    const float ev = esqp[cl];
#pragma unroll
    for (int mi = 0; mi < 4; ++mi)
#pragma unroll
      for (int reg = 0; reg < 4; ++reg) {
        const int row = wm + mi * 16 + quad * 4 + reg;
        base[(size_t)row * Ndim + n0 + cl] = ev - 2.0f * acc[mi][ni][reg];
      }
  }
}

// ============================================================
// Fused select: split-K reduce (compile-time NZ, unrolled) + top-2
// + exact fp32 refine + one-hot write
// ============================================================
template <int NZ>
__global__ __launch_bounds__(256) void k_select_t(const float* __restrict__ part,
                                                  const float* __restrict__ x,
                                                  const float* __restrict__ e,
                                                  float* __restrict__ out) {
  __shared__ float sv1[256], sv2[256];
  __shared__ int   si1[256], si2[256];
  __shared__ float s1[256], s2[256];
  __shared__ int win_sh;
  const int b = blockIdx.x, t = threadIdx.x;

  float v1 = 3.4e38f, v2 = 3.4e38f; int i1 = 0, i2 = 1;
  auto upd = [&](float v, int idx) {
    if (v < v1)      { v2 = v1; i2 = i1; v1 = v; i1 = idx; }
    else if (v < v2) { v2 = v;  i2 = idx; }
  };
#pragma unroll
  for (int i = 0; i < Ndim / 4 / 256; ++i) {
    int q = t + i * 256;  // float4 index over n
    float sx = 0.f, sy = 0.f, sz = 0.f, sw = 0.f;
#pragma unroll
    for (int z = 0; z < NZ; ++z) {
      float4 v = ((const float4*)part)[((size_t)z * Mdim + b) * (Ndim / 4) + q];
      sx += v.x; sy += v.y; sz += v.z; sw += v.w;
    }
    upd(sx, 4 * q + 0); upd(sy, 4 * q + 1); upd(sz, 4 * q + 2); upd(sw, 4 * q + 3);
  }
  sv1[t] = v1; si1[t] = i1; sv2[t] = v2; si2[t] = i2;
  __syncthreads();
  for (int sOff = 128; sOff > 0; sOff >>= 1) {
    if (t < sOff) {
      float bv1 = sv1[t + sOff], bv2 = sv2[t + sOff];
      int   bi1 = si1[t + sOff], bi2 = si2[t + sOff];
      float av1 = sv1[t],        av2 = sv2[t];
      int   ai1 = si1[t],        ai2 = si2[t];
      if (bv1 < av1)      { av2 = av1; ai2 = ai1; av1 = bv1; ai1 = bi1; }
      else if (bv1 < av2) { av2 = bv1; ai2 = bi1; }
      if (bv2 < av2)      { av2 = bv2; ai2 = bi2; }
      sv1[t] = av1; si1[t] = ai1; sv2[t] = av2; si2[t] = ai2;
    }
    __syncthreads();
  }
  const int c1 = si1[0], c2 = si2[0];

  // exact fp32 distances for the two candidates
  const float4* xb = (const float4*)(x + (size_t)b  * Kdim);
  const float4* e1 = (const float4*)(e + (size_t)c1 * Kdim);
  const float4* e2 = (const float4*)(e + (size_t)c2 * Kdim);
  float a1 = 0.f, a2 = 0.f;
#pragma unroll 4
  for (int i = 0; i < Kdim / 4 / 256; ++i) {
    int q = t + i * 256;
    float4 xv  = xb[q];
    float4 ev1 = e1[q];
    float4 ev2 = e2[q];
    a1 += ev1.x * (ev1.x - 2.f * xv.x) + ev1.y * (ev1.y - 2.f * xv.y)
        + ev1.z * (ev1.z - 2.f * xv.z) + ev1.w * (ev1.w - 2.f * xv.w);
    a2 += ev2.x * (ev2.x - 2.f * xv.x) + ev2.y * (ev2.y - 2.f * xv.y)
        + ev2.z * (ev2.z - 2.f * xv.z) + ev2.w * (ev2.w - 2.f * xv.w);
  }
  s1[t] = a1; s2[t] = a2;
  __syncthreads();
  for (int sOff = 128; sOff > 0; sOff >>= 1) {
    if (t < sOff) { s1[t] += s1[t + sOff]; s2[t] += s2[t + sOff]; }
    __syncthreads();
  }
  if (t == 0) {
    float d1 = s1[0], d2 = s2[0];
    win_sh = (d2 < d1 || (d2 == d1 && c2 < c1)) ? c2 : c1;  // np.argmin tie: smaller idx
  }
  __syncthreads();

  const int win = win_sh;
  float* outb = out + (size_t)b * Ndim;
#pragma unroll
  for (int g = 0; g < 4; ++g) {
    int q = g * 256 + t;
    float4 v;
    v.x = (win == 4 * q + 0) ? 1.f : 0.f;
    v.y = (win == 4 * q + 1) ? 1.f : 0.f;
    v.z = (win == 4 * q + 2) ? 1.f : 0.f;
    v.w = (win == 4 * q + 3) ? 1.f : 0.f;
    ((float4*)outb)[q] = v;
  }
}

// ============================================================
// Fallback tier (tiny/no workspace): fused gemm with atomics into out.
// ============================================================
__global__ __launch_bounds__(256) void k_gemm_fused(const float* __restrict__ x,
                                                    const float* __restrict__ e,
                                                    float* __restrict__ dst,
                                                    int ws_mode) {
  __shared__ short lds[2][2][4][128][8];
  __shared__ float esq_part[256];
  __shared__ float esq_sh[128];
  const int t  = threadIdx.x;
  const int n0 = blockIdx.x * FNT;
  const int m0 = blockIdx.y * FMT;
  const int kz = blockIdx.z;
  const int KCF = Kdim / KS_MID;
  const int NITF = KCF / FBK;
  const int k0 = kz * KCF;
  const int r  = t >> 1;
  const int kq = (t & 1) * 16;
  const int g0 = (t & 1) * 2;
  const float* xp = x + (size_t)(m0 + r) * Kdim + k0 + kq;
  const float* ep = e + (size_t)(n0 + r) * Kdim + k0 + kq;
  const int wave = t >> 6, lane = t & 63;
  const int wm = (wave & 1) * 64, wn = (wave >> 1) * 64;
  const int lcol = lane & 15, quad = lane >> 4;

  f32x4 acc[4][4] = {};
  float esq_acc = 0.0f;
  float4 bufA[4], bufB[4];
#pragma unroll
  for (int g = 0; g < 4; ++g) {
    bufA[g] = ((const float4*)xp)[g];
    bufB[g] = ((const float4*)ep)[g];
  }
  auto stagef = [&](int buf) {
    union { short8 s; unsigned int u[4]; } pa0, pa1, pb0, pb1;
    pa0.u[0] = cvt2(bufA[0].x, bufA[0].y); pa0.u[1] = cvt2(bufA[0].z, bufA[0].w);
    pa0.u[2] = cvt2(bufA[1].x, bufA[1].y); pa0.u[3] = cvt2(bufA[1].z, bufA[1].w);
    pa1.u[0] = cvt2(bufA[2].x, bufA[2].y); pa1.u[1] = cvt2(bufA[2].z, bufA[2].w);
    pa1.u[2] = cvt2(bufA[3].x, bufA[3].y); pa1.u[3] = cvt2(bufA[3].z, bufA[3].w);
    pb0.u[0] = cvt2(bufB[0].x, bufB[0].y); pb0.u[1] = cvt2(bufB[0].z, bufB[0].w);
    pb0.u[2] = cvt2(bufB[1].x, bufB[1].y); pb0.u[3] = cvt2(bufB[1].z, bufB[1].w);
    pb1.u[0] = cvt2(bufB[2].x, bufB[2].y); pb1.u[1] = cvt2(bufB[2].z, bufB[2].w);
    pb1.u[2] = cvt2(bufB[3].x, bufB[3].y); pb1.u[3] = cvt2(bufB[3].z, bufB[3].w);
#pragma unroll
    for (int g = 0; g < 4; ++g)
      esq_acc += bufB[g].x * bufB[g].x + bufB[g].y * bufB[g].y
               + bufB[g].z * bufB[g].z + bufB[g].w * bufB[g].w;
    *(short8*)&lds[buf][0][g0    ][r][0] = pa0.s;
    *(short8*)&lds[buf][0][g0 + 1][r][0] = pa1.s;
    *(short8*)&lds[buf][1][g0    ][r][0] = pb0.s;
    *(short8*)&lds[buf][1][g0 + 1][r][0] = pb1.s;
  };
  stagef(0);
  __syncthreads();
  for (int it = 0; it < NITF; ++it) {
    const int cur = it & 1;
    if (it + 1 < NITF) {
      const float* xn = xp + (size_t)(it + 1) * FBK;
      const float* en = ep + (size_t)(it + 1) * FBK;
#pragma unroll
      for (int g = 0; g < 4; ++g) {
        bufA[g] = ((const float4*)xn)[g];
        bufB[g] = ((const float4*)en)[g];
      }
    }
    short8 af[4], bfr[4];
#pragma unroll
    for (int mi = 0; mi < 4; ++mi)
      af[mi] = *(const short8*)&lds[cur][0][quad][wm + mi * 16 + lcol][0];
#pragma unroll
    for (int ni = 0; ni < 4; ++ni)
      bfr[ni] = *(const short8*)&lds[cur][1][quad][wn + ni * 16 + lcol][0];
#pragma unroll
    for (int mi = 0; mi < 4; ++mi)
#pragma unroll
      for (int ni = 0; ni < 4; ++ni)
        acc[mi][ni] = __builtin_amdgcn_mfma_f32_16x16x32_bf16(af[mi], bfr[ni], acc[mi][ni], 0, 0, 0);
    if (it + 1 < NITF) {
      stagef(cur ^ 1);
      __syncthreads();
    }
  }
  esq_part[t] = esq_acc;
  __syncthreads();
  if (t < 128) esq_sh[t] = esq_part[2 * t] + esq_part[2 * t + 1];
  __syncthreads();
  if (ws_mode) {
    float* base = dst + (size_t)kz * Mdim * Ndim;
#pragma unroll
    for (int mi = 0; mi < 4; ++mi)
#pragma unroll
      for (int ni = 0; ni < 4; ++ni)
#pragma unroll
        for (int reg = 0; reg < 4; ++reg) {
          int row = m0 + wm + mi * 16 + quad * 4 + reg;
          int cl  = wn + ni * 16 + lcol;
          base[(size_t)row * Ndim + n0 + cl] = esq_sh[cl] - 2.0f * acc[mi][ni][reg];
        }
  } else {
#pragma unroll
    for (int mi = 0; mi < 4; ++mi)
#pragma unroll
      for (int ni = 0; ni < 4; ++ni)
#pragma unroll
        for (int reg = 0; reg < 4; ++reg) {
          int row = m0 + wm + mi * 16 + quad * 4 + reg;
          int cl  = wn + ni * 16 + lcol;
          atomicAdd(&dst[(size_t)row * Ndim + n0 + cl], esq_sh[cl] - 2.0f * acc[mi][ni][reg]);
        }
  }
}

extern "C" void kernel_launch(void* const* d_in, const int* in_sizes, int n_in,
                              void* d_out, int out_size, void* d_ws, size_t ws_size,
                              hipStream_t stream) {
  (void)in_sizes; (void)n_in; (void)out_size;
  const float* x = (const float*)d_in[0];  // [256, 16384] fp32
  const float* e = (const float*)d_in[1];  // [4096, 16384] fp32
  float* out = (float*)d_out;
  char* ws = (char*)d_ws;

  if (ws_size >= NEED_FAST) {
    unsigned short* x_swz = (unsigned short*)(ws + X_SWZ_OFF);
    float* part = (float*)(ws + PART_OFF);
    hipLaunchKernelGGL(k_prep, dim3(256), dim3(256), 0, stream, x, x_swz);
    hipLaunchKernelGGL(k_gemm_f, dim3(Ndim / 64, KS), dim3(512), 0, stream,
                       x_swz, e, part);
    hipLaunchKernelGGL(k_select_t<KS>, dim3(Mdim), dim3(256), 0, stream, part, x, e, out);
  } else if (ws_size >= (size_t)KS_MID * Mdim * Ndim * 4) {
    float* part = (float*)ws;
    hipLaunchKernelGGL(k_gemm_fused, dim3(Ndim / FNT, Mdim / FMT, KS_MID), dim3(256), 0, stream,
                       x, e, part, 1);
    hipLaunchKernelGGL(k_select_t<KS_MID>, dim3(Mdim), dim3(256), 0, stream, part, x, e, out);
  } else {
    hipMemsetAsync(d_out, 0, (size_t)Mdim * Ndim * sizeof(float), stream);
    hipLaunchKernelGGL(k_gemm_fused, dim3(Ndim / FNT, Mdim / FMT, KS_MID), dim3(256), 0, stream,
                       x, e, out, 0);
    hipLaunchKernelGGL(k_select_t<1>, dim3(Mdim), dim3(256), 0, stream, out, x, e, out);
  }
}